// Round 4
// baseline (258.749 us; speedup 1.0000x reference)
//
#include <hip/hip_runtime.h>
#include <hip/hip_cooperative_groups.h>
#include <math.h>

namespace cg = cooperative_groups;

#define MG   2001          // NpointsMesh
#define KH   1001          // k = 0..1000
#define BATCH 16
#define NPTS  1024
#define RW    8
#define TAPS  (2*RW+1)

#define NBLK 512
#define NFC  448           // fcomp blocks = 8 mb x 2 ch x 28 ks
#define KSPL 28
#define KCH  36            // 28*36 = 1008 >= 1001
#define PSPL 4             // spread blocks per batch
#define DSPL 16
#define NDC  126           // 16*126 = 2016 >= 2001

// ws float offsets (all regions fully written every launch; no zeroing needed)
#define FPART 0                            // [28 ks][2 ch][2048]
#define GPART (FPART + KSPL*2*2048)        // [16 b][4 pc][2048]
#define SPART (GPART + BATCH*PSPL*2048)    // [16 dsp][16 b][2 ch][2048]
#define FRED  (SPART + DSPL*BATCH*2*2048)  // [2][17]

static __device__ __forceinline__ int wrapM(int m) {
  if (m < 0) m += MG;
  else if (m >= MG) m -= MG;
  return m;
}

static __device__ __forceinline__ void taps_of(float xv, int& m0, float* w) {
  const double PI = 3.14159265358979323846;
  const double h = 2.0*PI/(double)MG;
  const float tauf = (float)(12.0/((double)MG*(double)MG));
  const float inv4tau = (float)(1.0/(4.0*(double)tauf));
  m0 = (int)floor((double)xv/h + 0.5);
  #pragma unroll
  for (int r = 0; r < TAPS; ++r) {
    double d = (double)xv - (double)(m0 + r - RW)*h;
    float df = (float)d;
    w[r] = __expf(-(df*df)*inv4tau);
  }
}

__global__ void __launch_bounds__(256) k_all(float* __restrict__ ws,
                                             const float* __restrict__ x,
                                             const float* __restrict__ s0p,
                                             const float* __restrict__ s1p,
                                             const float* __restrict__ a0p,
                                             const float* __restrict__ a1p,
                                             float* __restrict__ out) {
  cg::grid_group grid = cg::this_grid();
  __shared__ __align__(16) float sm[2304];   // 9216 B
  const int tid = threadIdx.x;
  const int blk = blockIdx.x;
  const double PI = 3.14159265358979323846;

  // ---------------- Phase A: filter partials + spread ----------------
  if (blk < NFC) {
    // f partial: f[ch][m] += sum_{k in chunk ks} dk[ch][k]*cos(2*pi*k*m/M)
    const int mb = blk & 7, ch = (blk >> 3) & 1, ks = blk >> 4;
    const int k0 = ks * KCH;
    float* ct = sm;          // [2001]
    float* dk = sm + 2016;   // [KCH]
    for (int j = tid; j < MG; j += 256)
      ct[j] = (float)cos(2.0*PI*(double)j/(double)MG);
    if (tid < KCH) {
      int k = k0 + tid;
      float v = 0.f;
      if (k < KH) {
        float s  = (ch == 0) ? s0p[0] : s1p[0];
        float a  = (ch == 0) ? a0p[0] : a1p[0];
        float mu = (ch == 0) ? 1.0f : 0.5f;
        double tau = (double)(float)(12.0/((double)MG*(double)MG));
        double mus = (double)(mu*s);
        double kk = (double)k*(double)k;
        double deconv2 = (PI/tau)*exp(2.0*kk*tau);
        double mult = (double)a*4.0*PI/(kk + mus*mus);
        double C = 1.0/(2.0*PI*(double)MG*(double)MG);
        v = (float)(C*deconv2*mult*((k == 0) ? 1.0 : 2.0));
      }
      dk[tid] = v;
    }
    __syncthreads();
    const int m = mb*256 + tid;              // 0..2047
    float acc = 0.f;
    if (m < MG) {
      int j = (k0*m) % MG;
      #pragma unroll 4
      for (int t = 0; t < KCH; ++t) {
        acc = fmaf(dk[t], ct[j], acc);
        j += m; if (j >= MG) j -= MG;
      }
    }
    ws[FPART + (ks*2 + ch)*2048 + m] = acc;  // m>=MG slots hold 0
  } else {
    // spread partial: G[b][pc][m] = sum over this block's 256 points
    const int sb = blk - NFC;                // 0..63
    const int b = sb >> 2, pc = sb & 3;
    float* Gs = sm;
    for (int j = tid; j < MG; j += 256) Gs[j] = 0.f;
    __syncthreads();
    const float xv = x[b*NPTS + pc*256 + tid];
    int m0; float w[TAPS];
    taps_of(xv, m0, w);
    #pragma unroll
    for (int r = 0; r < TAPS; ++r)
      atomicAdd(&Gs[wrapM(m0 + r - RW)], w[r]);
    __syncthreads();
    float* Gp = &ws[GPART + (b*PSPL + pc)*2048];
    for (int j = tid; j < MG; j += 256) Gp[j] = Gs[j];
  }

  grid.sync();

  // ---------------- Phase B: d-split circular convolution ----------------
  {
    const int dsp = blk >> 5, b = (blk >> 1) & 15, mb = blk & 1;
    const int d0 = dsp * NDC;
    const int m0 = mb * 1024;
    float* GW  = sm;          // [1280]
    float* FW1 = sm + 1280;   // [128]
    float* FW2 = sm + 1408;   // [128]

    int baseP = (((m0 - d0 - 256) % MG) + MG) % MG;
    const float* g0 = &ws[GPART + b*PSPL*2048];
    for (int i = tid; i < 1280; i += 256) {
      int idx = baseP + i;
      if (idx >= MG) idx -= MG;
      GW[i] = g0[idx] + g0[2048 + idx] + g0[4096 + idx] + g0[6144 + idx];
    }
    if (tid < 128) {
      float v = 0.f;
      if (tid < NDC) {
        int dd = d0 + tid;
        #pragma unroll 4
        for (int ks = 0; ks < KSPL; ++ks) v += ws[FPART + (ks*2 + 0)*2048 + dd];
      }
      FW1[tid] = v;
    } else {
      int j = tid - 128; float v = 0.f;
      if (j < NDC) {
        int dd = d0 + j;
        #pragma unroll 4
        for (int ks = 0; ks < KSPL; ++ks) v += ws[FPART + (ks*2 + 1)*2048 + dd];
      }
      FW2[j] = v;
    }
    __syncthreads();

    const float4* GW4 = reinterpret_cast<const float4*>(GW);
    const float4* F14 = reinterpret_cast<const float4*>(FW1);
    const float4* F24 = reinterpret_cast<const float4*>(FW2);

    float4 prev = GW4[tid + 64];      // G[m - d0 + (0..3)]
    float acc1[4] = {0.f,0.f,0.f,0.f};
    float acc2[4] = {0.f,0.f,0.f,0.f};

    #pragma unroll 2
    for (int t = 0; t < 32; ++t) {
      float4 nv = GW4[tid + 63 - t];
      float4 f1 = F14[t];
      float4 f2 = F24[t];
      const float pw[4] = {prev.x, prev.y, prev.z, prev.w};
      const float nw[4] = {nv.x, nv.y, nv.z, nv.w};
      const float fj1[4] = {f1.x, f1.y, f1.z, f1.w};
      const float fj2[4] = {f2.x, f2.y, f2.z, f2.w};
      #pragma unroll
      for (int j = 0; j < 4; ++j) {
        #pragma unroll
        for (int s = 0; s < 4; ++s) {
          float wv = (s >= j) ? pw[s-j] : nw[4+s-j];
          acc1[s] = fmaf(fj1[j], wv, acc1[s]);
          acc2[s] = fmaf(fj2[j], wv, acc2[s]);
        }
      }
      prev = nv;
    }

    float* S1 = &ws[SPART + ((dsp*BATCH + b)*2 + 0)*2048];
    float* S2 = S1 + 2048;
    #pragma unroll
    for (int s = 0; s < 4; ++s) {
      int m = m0 + 4*tid + s;
      S1[m] = acc1[s];
      S2[m] = acc2[s];
    }

    // reduce the 34 filter head values energy's self-term needs
    if (blk == 0 && tid < 34) {
      int ch = tid / 17, dl = tid % 17;
      float v = 0.f;
      #pragma unroll 4
      for (int ks = 0; ks < KSPL; ++ks) v += ws[FPART + (ks*2 + ch)*2048 + dl];
      ws[FRED + ch*17 + dl] = v;
    }
  }

  grid.sync();

  // ---------------- Phase C: energies ----------------
  if (blk < 64) {
    const int gid = blk*256 + tid;           // 16384 points
    const int b = gid >> 10;
    const float xv = x[gid];
    int m0; float w[TAPS];
    taps_of(xv, m0, w);
    float c1 = 0.f, c2 = 0.f;
    #pragma unroll 1
    for (int r = 0; r < TAPS; ++r) {
      int mw = wrapM(m0 + r - RW);
      float s1v = 0.f, s2v = 0.f;
      #pragma unroll
      for (int dsp = 0; dsp < DSPL; ++dsp) {
        const float* Sp = &ws[SPART + (dsp*BATCH + b)*2*2048];
        s1v += Sp[mw];
        s2v += Sp[2048 + mw];
      }
      c1 = fmaf(w[r], s1v, c1);
      c2 = fmaf(w[r], s2v, c2);
    }
    float s1 = 0.f, s2 = 0.f;
    #pragma unroll
    for (int dl = 0; dl <= 2*RW; ++dl) {
      float c = 0.f;
      #pragma unroll
      for (int r = 0; r + dl < TAPS; ++r) c = fmaf(w[r], w[r + dl], c);
      float fac = (dl == 0) ? 1.f : 2.f;
      s1 = fmaf(fac*c, ws[FRED + dl], s1);
      s2 = fmaf(fac*c, ws[FRED + 17 + dl], s2);
    }
    out[gid*2 + 0] = c1 - s1;
    out[gid*2 + 1] = c2 - s2;
  }
}

extern "C" void kernel_launch(void* const* d_in, const int* in_sizes, int n_in,
                              void* d_out, int out_size, void* d_ws, size_t ws_size,
                              hipStream_t stream) {
  const float* x  = (const float*)d_in[0];
  const float* s0 = (const float*)d_in[1];
  const float* s1 = (const float*)d_in[2];
  const float* a0 = (const float*)d_in[3];
  const float* a1 = (const float*)d_in[4];
  float* ws  = (float*)d_ws;
  float* out = (float*)d_out;

  void* args[7] = {(void*)&ws, (void*)&x, (void*)&s0, (void*)&s1,
                   (void*)&a0, (void*)&a1, (void*)&out};
  hipLaunchCooperativeKernel((const void*)k_all, dim3(NBLK), dim3(256),
                             args, 0, stream);
}

// Round 5
// 117.255 us; speedup vs baseline: 2.2067x; 2.2067x over previous
//
#include <hip/hip_runtime.h>
#include <math.h>

#define MG    2001
#define KH    1001
#define BATCH 16
#define NPTS  1024
#define RW    8
#define TAPS  17

// K2 geometry: 9 chunks of 240 m-values (last = 81)
#define LEN   240
#define NMC   9
#define K2T   512

// K2 LDS float offsets (all quad-aligned)
#define F1o   0            // f ch0 [2008] (pad 2001..2007 = 0)
#define F2o   2008         // f ch1 [2008]
#define GLo   4016         // G_lds [2004]
#define GXo   6020         // Gx swizzled [2272]
#define SLo   8292         // S [2][256]
#define SMSZ  8804         // 35216 B

static __device__ __forceinline__ int wrapM(int m) {
  if (m < 0) m += MG;
  else if (m >= MG) m -= MG;
  return m;
}

static __device__ __forceinline__ void taps_of(float xv, int& m0, float* w) {
  const double PI = 3.14159265358979323846;
  const double h = 2.0*PI/(double)MG;
  const float tauf = (float)(12.0/((double)MG*(double)MG));
  const float inv4tau = (float)(1.0/(4.0*(double)tauf));
  m0 = (int)floor((double)xv/h + 0.5);
  #pragma unroll
  for (int r = 0; r < TAPS; ++r) {
    double d = (double)xv - (double)(m0 + r - RW)*h;
    float df = (float)d;
    w[r] = __expf(-(df*df)*inv4tau);
  }
}

// ---------------- K1: reduced filter f[2][2001] -> ws ----------------
// 64 blocks x 256: blk = (mg<<1)|ch ; thread = (ml, kq) ; k-split x4 + shfl reduce
__global__ void __launch_bounds__(256) k_filt(float* __restrict__ ws,
    const float* __restrict__ s0p, const float* __restrict__ s1p,
    const float* __restrict__ a0p, const float* __restrict__ a1p) {
  __shared__ float ct[MG];
  __shared__ float dk[KH];
  const int tid = threadIdx.x;
  const int ch = blockIdx.x & 1;
  const int mg = blockIdx.x >> 1;
  const double PI = 3.14159265358979323846;
  const float cstep = (float)(2.0*PI/(double)MG);
  for (int j = tid; j < MG; j += 256) ct[j] = __cosf(cstep * (float)j);
  {
    const float s  = (ch == 0) ? s0p[0] : s1p[0];
    const float a  = (ch == 0) ? a0p[0] : a1p[0];
    const float mu = (ch == 0) ? 1.0f : 0.5f;
    const double tau = (double)(float)(12.0/((double)MG*(double)MG));
    const double mus = (double)(mu*s);
    const double C = 1.0/(2.0*PI*(double)MG*(double)MG);
    for (int k = tid; k < KH; k += 256) {
      double kk = (double)k*(double)k;
      double v = C * (PI/tau)*exp(2.0*kk*tau)
                   * ((double)a*4.0*PI/(kk + mus*mus));
      dk[k] = (float)(v * ((k == 0) ? 1.0 : 2.0));
    }
  }
  __syncthreads();
  const int ml = tid >> 2, kq = tid & 3;
  const int m = mg*64 + ml;                 // 0..2047
  float acc = 0.f;
  if (m < MG) {
    const int k0 = kq*251, k1 = (kq == 3) ? KH : (k0 + 251);
    int j = (k0 * m) % MG;
    for (int k = k0; k < k1; ++k) {
      acc = fmaf(dk[k], ct[j], acc);
      j += m; if (j >= MG) j -= MG;
    }
  }
  acc += __shfl_xor(acc, 1);
  acc += __shfl_xor(acc, 2);
  if (kq == 0 && m < MG) ws[ch*2048 + m] = acc;
}

// swizzled quad accessor for Gx (breaks the 64B-stride 8-way bank conflict)
static __device__ __forceinline__ float4 gxq(const float* sm, int q) {
  return *(const float4*)&sm[GXo + (((q) ^ ((q >> 4) & 3)) << 2)];
}

// ---------------- K2: per-(batch, m-chunk) spread+conv+energy ----------------
__global__ void __launch_bounds__(K2T) k_main(const float* __restrict__ ws,
    const float* __restrict__ x, float* __restrict__ out) {
  __shared__ __align__(16) float sm[SMSZ];
  const int tid = threadIdx.x;
  const int mc = blockIdx.x;
  const int b  = blockIdx.y;
  const int lo = mc * LEN;

  // ---- step 1: zero G/S, load f, load my 2 points ----
  for (int j = tid; j < 2004; j += K2T) sm[GLo + j] = 0.f;
  sm[SLo + tid] = 0.f;                       // 512 = K2T
  for (int j = tid; j < MG; j += K2T) {
    sm[F1o + j] = ws[j];
    sm[F2o + j] = ws[2048 + j];
  }
  if (tid < 7) { sm[F1o + MG + tid] = 0.f; sm[F2o + MG + tid] = 0.f; }
  const float xv0 = x[b*NPTS + tid];
  const float xv1 = x[b*NPTS + tid + K2T];
  __syncthreads();

  // ---- step 2: spread this batch's 1024 points into G_lds ----
  {
    int m0; float w[TAPS];
    taps_of(xv0, m0, w);
    #pragma unroll
    for (int r = 0; r < TAPS; ++r)
      atomicAdd(&sm[GLo + wrapM(m0 + r - RW)], w[r]);
    taps_of(xv1, m0, w);
    #pragma unroll
    for (int r = 0; r < TAPS; ++r)
      atomicAdd(&sm[GLo + wrapM(m0 + r - RW)], w[r]);
  }
  __syncthreads();

  // ---- step 3: build unwrapped swizzled Gx: Gx[j] = G[(lo-2012+j) mod MG] ----
  {
    const int B0 = lo - 2012;
    for (int j = tid; j < 2264; j += K2T) {
      int idx = B0 + j;
      if (idx < 0) idx += MG;
      if (idx < 0) idx += MG;
      if (idx >= MG) idx -= MG;
      const int q = j >> 2;
      sm[GXo + ((q ^ ((q >> 4) & 3)) << 2) + (j & 3)] = sm[GLo + idx];
    }
  }
  __syncthreads();

  // ---- step 4: conv S[ch][m] = sum_d f[d]*G[m-d], 16-m x 4-d register tile ----
  {
    const int ds = tid >> 5;            // 0..15 : d-chunk of 128 (last 84)
    const int ch = (tid >> 4) & 1;
    const int mo = tid & 15;            // 16-m group: m_base = lo-8+mo*16
    const int d0q = ds << 5;            // starting d quad
    const int nq = (ds == 15) ? 21 : 32;
    const int P0q = (mo*16 + 2004 - ds*128) >> 2;
    const float* fch = &sm[ch ? F2o : F1o];
    float acc[16];
    #pragma unroll
    for (int s = 0; s < 16; ++s) acc[s] = 0.f;
    float wf[20];                       // window: wf[j] <-> Gx[4*(P0q-1-t) + j]
    #pragma unroll
    for (int j = 0; j < 4; ++j)
      *(float4*)&wf[4 + 4*j] = gxq(sm, P0q + j);
    #pragma unroll 4
    for (int t = 0; t < nq; ++t) {
      *(float4*)&wf[0] = gxq(sm, P0q - 1 - t);
      const float4 fq = *(const float4*)&fch[(d0q + t) << 2];
      #pragma unroll
      for (int u = 0; u < 4; ++u) {
        const float fv = ((const float*)&fq)[u];
        #pragma unroll
        for (int s = 0; s < 16; ++s)
          acc[s] = fmaf(fv, wf[s - u + 4], acc[s]);
      }
      #pragma unroll
      for (int j = 15; j >= 0; --j) wf[j + 4] = wf[j];
    }
    #pragma unroll
    for (int s = 0; s < 16; ++s)
      atomicAdd(&sm[SLo + ch*256 + mo*16 + s], acc[s]);
  }
  __syncthreads();

  // ---- step 5: energy for points whose m0 lies in this chunk ----
  #pragma unroll
  for (int pp = 0; pp < 2; ++pp) {
    const int n = tid + pp*K2T;
    const float xv = pp ? xv1 : xv0;
    int m0; float w[TAPS];
    taps_of(xv, m0, w);
    int m0w = m0; if (m0w >= MG) m0w -= MG;
    const int off = m0w - lo;
    if (off >= 0 && off < LEN) {
      float c1 = 0.f, c2 = 0.f;
      #pragma unroll
      for (int r = 0; r < TAPS; ++r) {
        c1 = fmaf(w[r], sm[SLo + off + r], c1);
        c2 = fmaf(w[r], sm[SLo + 256 + off + r], c2);
      }
      float s1 = 0.f, s2 = 0.f;
      #pragma unroll
      for (int dl = 0; dl < TAPS; ++dl) {
        float c = 0.f;
        #pragma unroll
        for (int r = 0; r + dl < TAPS; ++r) c = fmaf(w[r], w[r + dl], c);
        const float fac = (dl == 0) ? 1.f : 2.f;
        s1 = fmaf(fac*c, sm[F1o + dl], s1);
        s2 = fmaf(fac*c, sm[F2o + dl], s2);
      }
      const int gid = b*NPTS + n;
      out[gid*2 + 0] = c1 - s1;
      out[gid*2 + 1] = c2 - s2;
    }
  }
}

extern "C" void kernel_launch(void* const* d_in, const int* in_sizes, int n_in,
                              void* d_out, int out_size, void* d_ws, size_t ws_size,
                              hipStream_t stream) {
  const float* x  = (const float*)d_in[0];
  const float* s0 = (const float*)d_in[1];
  const float* s1 = (const float*)d_in[2];
  const float* a0 = (const float*)d_in[3];
  const float* a1 = (const float*)d_in[4];
  float* ws  = (float*)d_ws;
  float* out = (float*)d_out;

  hipLaunchKernelGGL(k_filt, dim3(64), dim3(256), 0, stream, ws, s0, s1, a0, a1);
  hipLaunchKernelGGL(k_main, dim3(NMC, BATCH), dim3(K2T), 0, stream, ws, x, out);
}